// Round 10
// baseline (1116.238 us; speedup 1.0000x reference)
//
#include <hip/hip_runtime.h>
#include <math.h>

#define N_NODES 50000
#define E_EDGES 1600000
#define D_IN 128
#define H_DIM 64
#define R_REL 3
#define ETOT (E_EDGES + N_NODES)
#define NEG_SLOPE 0.2f

// radix-partition CSR build parameters
#define BSHIFT 7
#define BSIZE 128                              // dst nodes per bucket
#define NBUCK ((N_NODES + BSIZE - 1) / BSIZE)  // 391
#define CHUNK 7168                             // edges per block in passes A/B (56KB stage)
#define NBLK ((ETOT + CHUNK - 1) / CHUNK)      // 231
#define CCAP 5120                              // partC LDS stage capacity (40KB)

typedef int i32x2 __attribute__((ext_vector_type(2)));
typedef float f32x4 __attribute__((ext_vector_type(4)));

// ---------------- thread-tiled LDS GEMM + attention coefficients ----------------
// Block: 256 threads -> 128 nodes x 64 cols. Thread (tn 0..31, tc 0..7) computes
// an 8x8 micro-tile (4 rows x 8 cols x ... rows tn*4+i, cols tc*8+j).
// Per k4: 12 ds_read_b128 for 128 FMAs. blockIdx.y = relation.
template <int DIN>
__global__ __launch_bounds__(256) void gemm_alpha_kernel(
    const float* __restrict__ xin, size_t xin_rstride,
    const float* __restrict__ W, size_t W_rstride,
    const float* __restrict__ a_s, const float* __restrict__ a_d, size_t a_rstride,
    float* __restrict__ h, size_t h_rstride,
    float* __restrict__ as_out, float* __restrict__ ad_out, size_t v_rstride,
    int r0)
{
    int rr = blockIdx.y;
    int rW = r0 + rr;
    xin += (size_t)rr * xin_rstride;
    W += (size_t)rW * W_rstride;
    a_s += (size_t)rW * a_rstride;
    a_d += (size_t)rW * a_rstride;
    h += (size_t)rr * h_rstride;
    as_out += (size_t)rr * v_rstride;
    ad_out += (size_t)rr * v_rstride;

    constexpr int KC = 64;
    constexpr int XSTR = KC + 4;   // 68
    __shared__ __align__(16) float xls[128 * XSTR];  // 34.8 KB
    __shared__ __align__(16) float wls[KC * 64];     // 16 KB
    int t = threadIdx.x;
    int n0 = blockIdx.x * 128;
    int nrows = N_NODES - n0; if (nrows > 128) nrows = 128;
    int tn = t >> 3;   // 0..31 (row quad)
    int tc = t & 7;    // 0..7  (col octet)

    float4 acc[4][2] = {};

    for (int kc = 0; kc < DIN; kc += KC) {
        if (kc) __syncthreads();
        int nf4 = nrows * 16;
        for (int f = t; f < nf4; f += 256) {
            int row = f >> 4;
            int q = f & 15;
            float4 xv = *reinterpret_cast<const float4*>(
                xin + (size_t)(n0 + row) * DIN + kc + q * 4);
            *reinterpret_cast<float4*>(&xls[row * XSTR + q * 4]) = xv;
        }
        for (int f = t; f < KC * 16; f += 256) {
            int kk = f >> 4;
            int q = f & 15;
            *reinterpret_cast<float4*>(&wls[kk * 64 + q * 4]) =
                *reinterpret_cast<const float4*>(W + (size_t)(kc + kk) * 64 + q * 4);
        }
        __syncthreads();

#pragma unroll
        for (int k4 = 0; k4 < KC / 4; ++k4) {
            float4 av[4];
            float4 bv[4][2];
#pragma unroll
            for (int i = 0; i < 4; ++i)
                av[i] = *reinterpret_cast<const float4*>(
                    &xls[(tn * 4 + i) * XSTR + k4 * 4]);
#pragma unroll
            for (int u = 0; u < 4; ++u) {
                bv[u][0] = *reinterpret_cast<const float4*>(
                    &wls[(k4 * 4 + u) * 64 + tc * 8]);
                bv[u][1] = *reinterpret_cast<const float4*>(
                    &wls[(k4 * 4 + u) * 64 + tc * 8 + 4]);
            }
#pragma unroll
            for (int i = 0; i < 4; ++i) {
                const float ak[4] = {av[i].x, av[i].y, av[i].z, av[i].w};
#pragma unroll
                for (int u = 0; u < 4; ++u) {
                    acc[i][0].x = fmaf(ak[u], bv[u][0].x, acc[i][0].x);
                    acc[i][0].y = fmaf(ak[u], bv[u][0].y, acc[i][0].y);
                    acc[i][0].z = fmaf(ak[u], bv[u][0].z, acc[i][0].z);
                    acc[i][0].w = fmaf(ak[u], bv[u][0].w, acc[i][0].w);
                    acc[i][1].x = fmaf(ak[u], bv[u][1].x, acc[i][1].x);
                    acc[i][1].y = fmaf(ak[u], bv[u][1].y, acc[i][1].y);
                    acc[i][1].z = fmaf(ak[u], bv[u][1].z, acc[i][1].z);
                    acc[i][1].w = fmaf(ak[u], bv[u][1].w, acc[i][1].w);
                }
            }
        }
    }

    float4 as0 = *reinterpret_cast<const float4*>(a_s + tc * 8);
    float4 as1 = *reinterpret_cast<const float4*>(a_s + tc * 8 + 4);
    float4 ad0 = *reinterpret_cast<const float4*>(a_d + tc * 8);
    float4 ad1 = *reinterpret_cast<const float4*>(a_d + tc * 8 + 4);
#pragma unroll
    for (int i = 0; i < 4; ++i) {
        int node = n0 + tn * 4 + i;
        bool ok = node < N_NODES;
        if (ok) {
            *reinterpret_cast<float4*>(h + (size_t)node * 64 + tc * 8) = acc[i][0];
            *reinterpret_cast<float4*>(h + (size_t)node * 64 + tc * 8 + 4) = acc[i][1];
        }
        float vs = acc[i][0].x * as0.x + acc[i][0].y * as0.y +
                   acc[i][0].z * as0.z + acc[i][0].w * as0.w +
                   acc[i][1].x * as1.x + acc[i][1].y * as1.y +
                   acc[i][1].z * as1.z + acc[i][1].w * as1.w;
        float vd = acc[i][0].x * ad0.x + acc[i][0].y * ad0.y +
                   acc[i][0].z * ad0.z + acc[i][0].w * ad0.w +
                   acc[i][1].x * ad1.x + acc[i][1].y * ad1.y +
                   acc[i][1].z * ad1.z + acc[i][1].w * ad1.w;
#pragma unroll
        for (int m = 4; m >= 1; m >>= 1) {  // reduce over 8-lane col group
            vs += __shfl_xor(vs, m, 64);
            vd += __shfl_xor(vd, m, 64);
        }
        if (ok && tc == 0) {
            as_out[node] = vs;
            ad_out[node] = vd;
        }
    }
}

// ---------------- radix-partitioned CSR build (batched over relations) ----------------
// Pass A: per-block LDS histogram over NBUCK dst-buckets. bh layout: [r][blk][bucket]
__global__ __launch_bounds__(256) void partA_hist(const int* __restrict__ edge_index,
                                                  int* __restrict__ bh)
{
    __shared__ int hist[NBUCK];
    int t = threadIdx.x;
    int r = blockIdx.x / NBLK;
    int blk = blockIdx.x % NBLK;
    const int* dstE = edge_index + (size_t)r * 2 * E_EDGES + E_EDGES;
    for (int b = t; b < NBUCK; b += 256) hist[b] = 0;
    __syncthreads();
    int base = blk * CHUNK;
#pragma unroll 4
    for (int u = 0; u < CHUNK / 256; ++u) {
        int i = base + u * 256 + t;
        if (i < ETOT) {
            int d = (i < E_EDGES) ? dstE[i] : (i - E_EDGES);
            atomicAdd(&hist[d >> BSHIFT], 1);
        }
    }
    __syncthreads();
    int* bh_blk = bh + ((size_t)r * NBLK + blk) * NBUCK;
    for (int b = t; b < NBUCK; b += 256) bh_blk[b] = hist[b];
}

// Pass A2: per (r,bucket), exclusive scan of per-block counts -> bhoff + total.
__global__ __launch_bounds__(256) void partA2_scan(const int* __restrict__ bh,
                                                   int* __restrict__ bhoff,
                                                   int* __restrict__ btot)
{
    __shared__ int tmp[256];
    int r = blockIdx.x / NBUCK;
    int b = blockIdx.x % NBUCK;
    int t = threadIdx.x;
    const int* bh_r = bh + (size_t)r * NBLK * NBUCK;
    int* bhoff_r = bhoff + (size_t)r * NBLK * NBUCK;
    int v = (t < NBLK) ? bh_r[(size_t)t * NBUCK + b] : 0;   // NBLK=231 <= 256
    int x = v;
#pragma unroll
    for (int off = 1; off < 256; off <<= 1) {
        tmp[t] = x;
        __syncthreads();
        int a = (t >= off) ? tmp[t - off] : 0;
        __syncthreads();
        x += a;
    }
    if (t < NBLK) bhoff_r[(size_t)t * NBUCK + b] = x - v;
    if (t == 255) btot[r * NBUCK + b] = x;
}

// Pass A3: per relation, exclusive scan of bucket totals -> bucket bases.
__global__ __launch_bounds__(256) void partA3_scan(const int* __restrict__ btot,
                                                   int* __restrict__ bbase)
{
    __shared__ int tmp[256];
    __shared__ int carry_s;
    int r = blockIdx.x;
    int t = threadIdx.x;
    const int* row = btot + r * NBUCK;
    int* outb = bbase + r * (NBUCK + 1);
    if (t == 0) carry_s = 0;
    __syncthreads();
    for (int base = 0; base < NBUCK; base += 256) {
        int idx = base + t;
        int v = (idx < NBUCK) ? row[idx] : 0;
        int x = v;
#pragma unroll
        for (int off = 1; off < 256; off <<= 1) {
            tmp[t] = x;
            __syncthreads();
            int a = (t >= off) ? tmp[t - off] : 0;
            __syncthreads();
            x += a;
        }
        int carry = carry_s;
        if (idx < NBUCK) outb[idx] = carry + x - v;
        __syncthreads();
        if (t == 255) carry_s = carry + x;
        __syncthreads();
    }
    if (t == 0) outb[NBUCK] = carry_s;  // == ETOT
}

// Pass B: block-local LDS counting sort by bucket, then LINEAR coalesced write-out.
// Record: .x = src | (dst << 16) (both < 2^16), .y = w bits.
__global__ __launch_bounds__(256) void partB_scatter(
    const int* __restrict__ edge_index, const float* __restrict__ edge_weight,
    const int* __restrict__ bh, const int* __restrict__ bhoff,
    const int* __restrict__ bbase, int2* __restrict__ sedge)
{
    __shared__ int2 stage[CHUNK];     // 56 KB
    __shared__ int cur[NBUCK];
    __shared__ int gbase[NBUCK];
    __shared__ int tmp[256];
    __shared__ int carry_s;
    int t = threadIdx.x;
    int r = blockIdx.x / NBLK;
    int blk = blockIdx.x % NBLK;
    const int* srcE = edge_index + (size_t)r * 2 * E_EDGES;
    const int* dstE = srcE + E_EDGES;
    const float* ewr = edge_weight + (size_t)r * E_EDGES;
    const int* bh_blk = bh + ((size_t)r * NBLK + blk) * NBUCK;
    const int* bhoff_blk = bhoff + ((size_t)r * NBLK + blk) * NBUCK;
    const int* bbase_r = bbase + r * (NBUCK + 1);
    int2* se_r = sedge + (size_t)r * ETOT;

    if (t == 0) carry_s = 0;
    __syncthreads();
    for (int base = 0; base < NBUCK; base += 256) {
        int idx = base + t;
        int v = (idx < NBUCK) ? bh_blk[idx] : 0;
        int x = v;
#pragma unroll
        for (int off = 1; off < 256; off <<= 1) {
            tmp[t] = x;
            __syncthreads();
            int a = (t >= off) ? tmp[t - off] : 0;
            __syncthreads();
            x += a;
        }
        int carry = carry_s;
        if (idx < NBUCK) {
            int ls = carry + x - v;
            cur[idx] = ls;
            gbase[idx] = bbase_r[idx] + bhoff_blk[idx] - ls;
        }
        __syncthreads();
        if (t == 255) carry_s = carry + x;
        __syncthreads();
    }

    int base0 = blk * CHUNK;
    int chunkLen = ETOT - base0; if (chunkLen > CHUNK) chunkLen = CHUNK;
#pragma unroll 4
    for (int u = 0; u < CHUNK / 256; ++u) {
        int i = base0 + u * 256 + t;
        if (i < ETOT) {
            int s, d;
            float w;
            if (i < E_EDGES) {
                s = srcE[i]; d = dstE[i]; w = ewr[i];
            } else {
                s = d = i - E_EDGES; w = 1.0f;
            }
            int pos = atomicAdd(&cur[d >> BSHIFT], 1);  // LDS atomic
            int2 pay;
            pay.x = s | (d << 16);
            pay.y = __float_as_int(w);
            stage[pos] = pay;
        }
    }
    __syncthreads();
    for (int j = t; j < chunkLen; j += 256) {
        int2 rec = stage[j];
        int d = (int)(((unsigned)rec.x) >> 16);
        se_r[gbase[d >> BSHIFT] + j] = rec;
    }
}

// Pass C: per-bucket LDS-staged counting sort, IN PLACE in sedge -> rs + final {src,w}.
__global__ __launch_bounds__(256) void partC_sort(
    const int* __restrict__ bbase, int2* __restrict__ sedge,
    int* __restrict__ rs)
{
    __shared__ int2 stage[CCAP];   // 40 KB
    __shared__ int cnt[BSIZE];
    __shared__ int rsl[BSIZE];
    __shared__ int tmp[BSIZE];
    __shared__ int cur[BSIZE];
    int r = blockIdx.x / NBUCK;
    int b = blockIdx.x % NBUCK;
    int t = threadIdx.x;
    const int* bbase_r = bbase + r * (NBUCK + 1);
    int* rs_r = rs + r * (N_NODES + 1);
    int2* se_r = sedge + (size_t)r * ETOT;
    int lo = b * BSIZE;
    int nn = N_NODES - lo; if (nn > BSIZE) nn = BSIZE;
    int seg0 = bbase_r[b], seg1 = bbase_r[b + 1];
    int len = seg1 - seg0;
    if (t < BSIZE) { cnt[t] = 0; cur[t] = 0; }
    __syncthreads();
    for (int k = t; k < len; k += 256) {
        int2 pw = se_r[seg0 + k];   // coalesced read
        if (k < CCAP) stage[k] = pw;
        atomicAdd(&cnt[(pw.x >> 16) & (BSIZE - 1)], 1);
    }
    __syncthreads();
    int v = 0, x = 0;
    if (t < BSIZE) { v = cnt[t]; x = v; }
#pragma unroll
    for (int off = 1; off < BSIZE; off <<= 1) {
        if (t < BSIZE) tmp[t] = x;
        __syncthreads();
        int a = (t < BSIZE && t >= off) ? tmp[t - off] : 0;
        __syncthreads();
        x += a;
    }
    if (t < BSIZE) rsl[t] = x - v;  // local exclusive
    __syncthreads();
    if (t < nn) rs_r[lo + t] = seg0 + rsl[t];
    if (b == NBUCK - 1 && t == 0) rs_r[N_NODES] = seg1;
    for (int k = t; k < len; k += 256) {
        int2 pw = (k < CCAP) ? stage[k] : se_r[seg0 + k];
        int dlo = (pw.x >> 16) & (BSIZE - 1);
        int pos = rsl[dlo] + atomicAdd(&cur[dlo], 1);
        int2 rec;
        rec.x = pw.x & 0xFFFF;
        rec.y = pw.y;
        se_r[seg0 + pos] = rec;
    }
}

// ---------------- per-node softmax + aggregation (no max pass) ----------------
// One wave per dst node; blockIdx.y = relation. 2-stage pipelined gather with
// 4 independent accumulator chains. sedge loads are NONTEMPORAL (single-use
// stream; don't evict the h gather table from L2). Final-layer out stores nt.
__global__ __launch_bounds__(256) void agg_kernel(
    const int* __restrict__ rs, const int2* __restrict__ sedge,
    const float* __restrict__ as_v, const float* __restrict__ ad_v, size_t v_rstride,
    const float* __restrict__ h, size_t h_rstride,
    const float* __restrict__ bias, size_t b_rstride,
    float* __restrict__ out, size_t out_roffset, int out_stride, int do_relu,
    int r0)
{
    int rr = blockIdx.y;
    int rW = r0 + rr;
    rs += (size_t)rW * (N_NODES + 1);
    sedge += (size_t)rW * ETOT;
    as_v += (size_t)rr * v_rstride;
    ad_v += (size_t)rr * v_rstride;
    h += (size_t)rr * h_rstride;
    bias += (size_t)rW * b_rstride;
    out += (size_t)rr * out_roffset;

    int wave = (int)(((size_t)blockIdx.x * blockDim.x + threadIdx.x) >> 6);
    int lane = threadIdx.x & 63;
    if (wave >= N_NODES) return;
    int beg = rs[wave], end = rs[wave + 1];
    float ad_n = ad_v[wave];

    int sub = lane >> 4;   // edge sub-slot 0..3
    int f = lane & 15;     // feature quad index
    const float* hf = h + f * 4;

    float ssum = 0.f;
    float4 a0 = {0.f, 0.f, 0.f, 0.f};
    float4 a1 = a0, a2 = a0, a3 = a0;

    for (int cbeg = beg; cbeg < end; cbeg += 64) {
        int rem = end - cbeg;
        if (rem > 64) rem = 64;
        int srcv = 0;
        float pq = 0.f;
        if (lane < rem) {
            i32x2 pe = __builtin_nontemporal_load(
                reinterpret_cast<const i32x2*>(sedge + cbeg + lane));
            srcv = pe.x;
            float e = as_v[srcv] + ad_n;
            e = (e > 0.f) ? e : NEG_SLOPE * e;
            float p = __expf(e);
            ssum += p;
            pq = p * __int_as_float(pe.y);
        }
        int s0 = __shfl(srcv, sub, 64);
        float q0 = __shfl(pq, sub, 64);
        int s1 = __shfl(srcv, 4 + sub, 64);
        float q1 = __shfl(pq, 4 + sub, 64);
        int s2 = __shfl(srcv, 8 + sub, 64);
        float q2 = __shfl(pq, 8 + sub, 64);
        int s3 = __shfl(srcv, 12 + sub, 64);
        float q3 = __shfl(pq, 12 + sub, 64);
        float4 h0 = *reinterpret_cast<const float4*>(hf + (size_t)s0 * 64);
        float4 h1 = *reinterpret_cast<const float4*>(hf + (size_t)s1 * 64);
        float4 h2 = *reinterpret_cast<const float4*>(hf + (size_t)s2 * 64);
        float4 h3 = *reinterpret_cast<const float4*>(hf + (size_t)s3 * 64);
        for (int t0 = 16; t0 < rem; t0 += 16) {
            int ns0 = __shfl(srcv, t0 + sub, 64);
            float nq0 = __shfl(pq, t0 + sub, 64);
            int ns1 = __shfl(srcv, t0 + 4 + sub, 64);
            float nq1 = __shfl(pq, t0 + 4 + sub, 64);
            int ns2 = __shfl(srcv, t0 + 8 + sub, 64);
            float nq2 = __shfl(pq, t0 + 8 + sub, 64);
            int ns3 = __shfl(srcv, t0 + 12 + sub, 64);
            float nq3 = __shfl(pq, t0 + 12 + sub, 64);
            float4 nh0 = *reinterpret_cast<const float4*>(hf + (size_t)ns0 * 64);
            float4 nh1 = *reinterpret_cast<const float4*>(hf + (size_t)ns1 * 64);
            float4 nh2 = *reinterpret_cast<const float4*>(hf + (size_t)ns2 * 64);
            float4 nh3 = *reinterpret_cast<const float4*>(hf + (size_t)ns3 * 64);
            a0.x = fmaf(q0, h0.x, a0.x);
            a0.y = fmaf(q0, h0.y, a0.y);
            a0.z = fmaf(q0, h0.z, a0.z);
            a0.w = fmaf(q0, h0.w, a0.w);
            a1.x = fmaf(q1, h1.x, a1.x);
            a1.y = fmaf(q1, h1.y, a1.y);
            a1.z = fmaf(q1, h1.z, a1.z);
            a1.w = fmaf(q1, h1.w, a1.w);
            a2.x = fmaf(q2, h2.x, a2.x);
            a2.y = fmaf(q2, h2.y, a2.y);
            a2.z = fmaf(q2, h2.z, a2.z);
            a2.w = fmaf(q2, h2.w, a2.w);
            a3.x = fmaf(q3, h3.x, a3.x);
            a3.y = fmaf(q3, h3.y, a3.y);
            a3.z = fmaf(q3, h3.z, a3.z);
            a3.w = fmaf(q3, h3.w, a3.w);
            q0 = nq0; h0 = nh0;
            q1 = nq1; h1 = nh1;
            q2 = nq2; h2 = nh2;
            q3 = nq3; h3 = nh3;
        }
        a0.x = fmaf(q0, h0.x, a0.x);
        a0.y = fmaf(q0, h0.y, a0.y);
        a0.z = fmaf(q0, h0.z, a0.z);
        a0.w = fmaf(q0, h0.w, a0.w);
        a1.x = fmaf(q1, h1.x, a1.x);
        a1.y = fmaf(q1, h1.y, a1.y);
        a1.z = fmaf(q1, h1.z, a1.z);
        a1.w = fmaf(q1, h1.w, a1.w);
        a2.x = fmaf(q2, h2.x, a2.x);
        a2.y = fmaf(q2, h2.y, a2.y);
        a2.z = fmaf(q2, h2.z, a2.z);
        a2.w = fmaf(q2, h2.w, a2.w);
        a3.x = fmaf(q3, h3.x, a3.x);
        a3.y = fmaf(q3, h3.y, a3.y);
        a3.z = fmaf(q3, h3.z, a3.z);
        a3.w = fmaf(q3, h3.w, a3.w);
    }

    float4 acc;
    acc.x = (a0.x + a1.x) + (a2.x + a3.x);
    acc.y = (a0.y + a1.y) + (a2.y + a3.y);
    acc.z = (a0.z + a1.z) + (a2.z + a3.z);
    acc.w = (a0.w + a1.w) + (a2.w + a3.w);

#pragma unroll
    for (int off = 32; off > 0; off >>= 1) ssum += __shfl_xor(ssum, off, 64);
    acc.x += __shfl_xor(acc.x, 16, 64);
    acc.y += __shfl_xor(acc.y, 16, 64);
    acc.z += __shfl_xor(acc.z, 16, 64);
    acc.w += __shfl_xor(acc.w, 16, 64);
    acc.x += __shfl_xor(acc.x, 32, 64);
    acc.y += __shfl_xor(acc.y, 32, 64);
    acc.z += __shfl_xor(acc.z, 32, 64);
    acc.w += __shfl_xor(acc.w, 32, 64);

    if (sub == 0) {
        float inv = 1.f / (ssum + 1e-16f);
        const float4 bv = *reinterpret_cast<const float4*>(bias + f * 4);
        float4 o;
        o.x = fmaf(acc.x, inv, bv.x);
        o.y = fmaf(acc.y, inv, bv.y);
        o.z = fmaf(acc.z, inv, bv.z);
        o.w = fmaf(acc.w, inv, bv.w);
        float* dst = out + (size_t)wave * out_stride + f * 4;
        if (do_relu) {
            o.x = fmaxf(o.x, 0.f);
            o.y = fmaxf(o.y, 0.f);
            o.z = fmaxf(o.z, 0.f);
            o.w = fmaxf(o.w, 0.f);
            *reinterpret_cast<float4*>(dst) = o;   // xbuf: re-read by next gemm
        } else {
            f32x4 o4 = {o.x, o.y, o.z, o.w};       // final out: never re-read
            __builtin_nontemporal_store(o4, reinterpret_cast<f32x4*>(dst));
        }
    }
}

extern "C" void kernel_launch(void* const* d_in, const int* in_sizes, int n_in,
                              void* d_out, int out_size, void* d_ws, size_t ws_size,
                              hipStream_t stream)
{
    (void)in_sizes; (void)n_in; (void)out_size;
    const float* x = (const float*)d_in[0];
    const float* edge_weight = (const float*)d_in[1];
    const float* W0 = (const float*)d_in[2];
    const float* W1 = (const float*)d_in[3];
    const float* W2 = (const float*)d_in[4];
    const float* a_src = (const float*)d_in[5];
    const float* a_dst = (const float*)d_in[6];
    const float* bias = (const float*)d_in[7];
    const int* edge_index = (const int*)d_in[8];
    float* out = (float*)d_out;

    char* ws = (char*)d_ws;
    size_t off = 0;
    auto alloc = [&](size_t bytes) {
        void* p = ws + off;
        off += (bytes + 255) & ~(size_t)255;
        return p;
    };
    int2* sedge = (int2*)alloc((size_t)R_REL * ETOT * 8);        // 39.6 MB
    int* bh = (int*)alloc((size_t)R_REL * NBLK * NBUCK * 4);     // 1.08 MB
    int* bhoff = (int*)alloc((size_t)R_REL * NBLK * NBUCK * 4);  // 1.08 MB
    int* btot = (int*)alloc((size_t)R_REL * NBUCK * 4);
    int* bbase = (int*)alloc((size_t)R_REL * (NBUCK + 1) * 4);
    int* rs = (int*)alloc((size_t)R_REL * (N_NODES + 1) * 4);

    // batched path needs 3x node buffers (~78 MB extra); fall back if ws too small
    size_t per_rel = ((size_t)N_NODES * 64 * 4 * 2 + (size_t)N_NODES * 4 * 2 + 1024);
    int K = (ws_size >= off + 3 * per_rel + (1 << 20)) ? 3 : 1;
    float* hbuf = (float*)alloc((size_t)K * N_NODES * 64 * 4);
    float* xbuf = (float*)alloc((size_t)K * N_NODES * 64 * 4);
    float* asv = (float*)alloc((size_t)K * N_NODES * 4);
    float* adv = (float*)alloc((size_t)K * N_NODES * 4);

    const int WAVE_BLOCKS = (N_NODES * 64 + 255) / 256;  // 12500
    const int GEMM_BLOCKS = (N_NODES + 127) / 128;       // 391 (128 nodes/block)
    const size_t HS = (size_t)N_NODES * 64;              // per-relation h/x stride
    const size_t VS = (size_t)N_NODES;                   // per-relation asv/adv stride

    // batched CSR build for all 3 relations (5 launches, no global atomics)
    partA_hist<<<R_REL * NBLK, 256, 0, stream>>>(edge_index, bh);
    partA2_scan<<<R_REL * NBUCK, 256, 0, stream>>>(bh, bhoff, btot);
    partA3_scan<<<R_REL, 256, 0, stream>>>(btot, bbase);
    partB_scatter<<<R_REL * NBLK, 256, 0, stream>>>(edge_index, edge_weight,
                                                    bh, bhoff, bbase, sedge);
    partC_sort<<<R_REL * NBUCK, 256, 0, stream>>>(bbase, sedge, rs);

    if (K == 3) {
        // layer-lockstep: one gemm + one agg dispatch per layer, grid.y = 3 relations
        for (int i = 0; i < 3; ++i) {
            if (i == 0)
                gemm_alpha_kernel<D_IN><<<dim3(GEMM_BLOCKS, 3), 256, 0, stream>>>(
                    x, 0, W0, (size_t)D_IN * H_DIM,
                    a_src + i * H_DIM, a_dst + i * H_DIM, 3 * H_DIM,
                    hbuf, HS, asv, adv, VS, 0);
            else
                gemm_alpha_kernel<H_DIM><<<dim3(GEMM_BLOCKS, 3), 256, 0, stream>>>(
                    xbuf, HS, (i == 1 ? W1 : W2), (size_t)H_DIM * H_DIM,
                    a_src + i * H_DIM, a_dst + i * H_DIM, 3 * H_DIM,
                    hbuf, HS, asv, adv, VS, 0);
            if (i < 2)
                agg_kernel<<<dim3(WAVE_BLOCKS, 3), 256, 0, stream>>>(
                    rs, sedge, asv, adv, VS, hbuf, HS,
                    bias + i * H_DIM, 3 * H_DIM,
                    xbuf, HS, 64, 1, 0);
            else
                agg_kernel<<<dim3(WAVE_BLOCKS, 3), 256, 0, stream>>>(
                    rs, sedge, asv, adv, VS, hbuf, HS,
                    bias + i * H_DIM, 3 * H_DIM,
                    out, 64, 192, 0, 0);
        }
    } else {
        for (int r = 0; r < R_REL; ++r) {
            for (int i = 0; i < 3; ++i) {
                if (i == 0)
                    gemm_alpha_kernel<D_IN><<<dim3(GEMM_BLOCKS, 1), 256, 0, stream>>>(
                        x, 0, W0, (size_t)D_IN * H_DIM,
                        a_src + i * H_DIM, a_dst + i * H_DIM, 3 * H_DIM,
                        hbuf, 0, asv, adv, 0, r);
                else
                    gemm_alpha_kernel<H_DIM><<<dim3(GEMM_BLOCKS, 1), 256, 0, stream>>>(
                        xbuf, 0, (i == 1 ? W1 : W2), (size_t)H_DIM * H_DIM,
                        a_src + i * H_DIM, a_dst + i * H_DIM, 3 * H_DIM,
                        hbuf, 0, asv, adv, 0, r);
                if (i < 2)
                    agg_kernel<<<dim3(WAVE_BLOCKS, 1), 256, 0, stream>>>(
                        rs, sedge, asv, adv, 0, hbuf, 0,
                        bias + i * H_DIM, 3 * H_DIM,
                        xbuf, 0, 64, 1, r);
                else
                    agg_kernel<<<dim3(WAVE_BLOCKS, 1), 256, 0, stream>>>(
                        rs, sedge, asv, adv, 0, hbuf, 0,
                        bias + i * H_DIM, 3 * H_DIM,
                        out + r * 64, 0, 192, 0, r);
            }
        }
    }
}

// Round 11
// 720.694 us; speedup vs baseline: 1.5488x; 1.5488x over previous
//
#include <hip/hip_runtime.h>
#include <math.h>

#define N_NODES 50000
#define E_EDGES 1600000
#define D_IN 128
#define H_DIM 64
#define R_REL 3
#define ETOT (E_EDGES + N_NODES)
#define NEG_SLOPE 0.2f

// radix-partition CSR build parameters
#define BSHIFT 7
#define BSIZE 128                              // dst nodes per bucket
#define NBUCK ((N_NODES + BSIZE - 1) / BSIZE)  // 391
#define CHUNK 7168                             // edges per block in passes A/B (56KB stage)
#define NBLK ((ETOT + CHUNK - 1) / CHUNK)      // 231
#define CCAP 5120                              // partC LDS stage capacity (40KB)

typedef int i32x2 __attribute__((ext_vector_type(2)));
typedef float f32x4 __attribute__((ext_vector_type(4)));

// ---------------- thread-tiled LDS GEMM + attention coefficients ----------------
// Block: 256 threads -> 64 nodes x 64 cols. Thread (tn,tc) computes a 4x4 tile.
// (Round-9 proven version: VGPR ~44, no spill. The 8x8 variant spilled to
// scratch: VGPR 256 + 343MB WRITE. Keep 4x4.)
template <int DIN>
__global__ __launch_bounds__(256) void gemm_alpha_kernel(
    const float* __restrict__ xin, size_t xin_rstride,
    const float* __restrict__ W, size_t W_rstride,
    const float* __restrict__ a_s, const float* __restrict__ a_d, size_t a_rstride,
    float* __restrict__ h, size_t h_rstride,
    float* __restrict__ as_out, float* __restrict__ ad_out, size_t v_rstride,
    int r0)
{
    int rr = blockIdx.y;
    int rW = r0 + rr;
    xin += (size_t)rr * xin_rstride;
    W += (size_t)rW * W_rstride;
    a_s += (size_t)rW * a_rstride;
    a_d += (size_t)rW * a_rstride;
    h += (size_t)rr * h_rstride;
    as_out += (size_t)rr * v_rstride;
    ad_out += (size_t)rr * v_rstride;

    constexpr int KC = 64;
    constexpr int XSTR = KC + 4;
    __shared__ __align__(16) float xls[64 * XSTR];
    __shared__ __align__(16) float wls[KC * 64];
    int t = threadIdx.x;
    int n0 = blockIdx.x * 64;
    int nrows = N_NODES - n0; if (nrows > 64) nrows = 64;
    int tn = t >> 4;
    int tc = t & 15;

    float4 acc[4] = {{0,0,0,0},{0,0,0,0},{0,0,0,0},{0,0,0,0}};

    for (int kc = 0; kc < DIN; kc += KC) {
        if (kc) __syncthreads();
        int nf4 = nrows * (KC / 4);
        for (int f = t; f < nf4; f += 256) {
            int row = f >> 4;
            int q = f & 15;
            float4 xv = *reinterpret_cast<const float4*>(
                xin + (size_t)(n0 + row) * DIN + kc + q * 4);
            *reinterpret_cast<float4*>(&xls[row * XSTR + q * 4]) = xv;
        }
        for (int f = t; f < KC * 16; f += 256) {
            int kk = f >> 4;
            int q = f & 15;
            *reinterpret_cast<float4*>(&wls[kk * 64 + q * 4]) =
                *reinterpret_cast<const float4*>(W + (size_t)(kc + kk) * 64 + q * 4);
        }
        __syncthreads();

#pragma unroll
        for (int k4 = 0; k4 < KC / 4; ++k4) {
            float4 av[4], bv[4];
#pragma unroll
            for (int i = 0; i < 4; ++i)
                av[i] = *reinterpret_cast<const float4*>(
                    &xls[(tn * 4 + i) * XSTR + k4 * 4]);
#pragma unroll
            for (int u = 0; u < 4; ++u)
                bv[u] = *reinterpret_cast<const float4*>(
                    &wls[(k4 * 4 + u) * 64 + tc * 4]);
#pragma unroll
            for (int i = 0; i < 4; ++i) {
                acc[i].x = fmaf(av[i].x, bv[0].x, acc[i].x);
                acc[i].y = fmaf(av[i].x, bv[0].y, acc[i].y);
                acc[i].z = fmaf(av[i].x, bv[0].z, acc[i].z);
                acc[i].w = fmaf(av[i].x, bv[0].w, acc[i].w);
                acc[i].x = fmaf(av[i].y, bv[1].x, acc[i].x);
                acc[i].y = fmaf(av[i].y, bv[1].y, acc[i].y);
                acc[i].z = fmaf(av[i].y, bv[1].z, acc[i].z);
                acc[i].w = fmaf(av[i].y, bv[1].w, acc[i].w);
                acc[i].x = fmaf(av[i].z, bv[2].x, acc[i].x);
                acc[i].y = fmaf(av[i].z, bv[2].y, acc[i].y);
                acc[i].z = fmaf(av[i].z, bv[2].z, acc[i].z);
                acc[i].w = fmaf(av[i].z, bv[2].w, acc[i].w);
                acc[i].x = fmaf(av[i].w, bv[3].x, acc[i].x);
                acc[i].y = fmaf(av[i].w, bv[3].y, acc[i].y);
                acc[i].z = fmaf(av[i].w, bv[3].z, acc[i].z);
                acc[i].w = fmaf(av[i].w, bv[3].w, acc[i].w);
            }
        }
    }

    float4 asj = *reinterpret_cast<const float4*>(a_s + tc * 4);
    float4 adj = *reinterpret_cast<const float4*>(a_d + tc * 4);
#pragma unroll
    for (int i = 0; i < 4; ++i) {
        int node = n0 + tn * 4 + i;
        bool ok = node < N_NODES;
        if (ok)
            *reinterpret_cast<float4*>(h + (size_t)node * 64 + tc * 4) = acc[i];
        float vs = acc[i].x * asj.x + acc[i].y * asj.y +
                   acc[i].z * asj.z + acc[i].w * asj.w;
        float vd = acc[i].x * adj.x + acc[i].y * adj.y +
                   acc[i].z * adj.z + acc[i].w * adj.w;
#pragma unroll
        for (int m = 8; m >= 1; m >>= 1) {
            vs += __shfl_xor(vs, m, 64);
            vd += __shfl_xor(vd, m, 64);
        }
        if (ok && tc == 0) {
            as_out[node] = vs;
            ad_out[node] = vd;
        }
    }
}

// ---------------- radix-partitioned CSR build (batched over relations) ----------------
// Pass A: per-block LDS histogram over NBUCK dst-buckets. bh layout: [r][blk][bucket]
__global__ __launch_bounds__(256) void partA_hist(const int* __restrict__ edge_index,
                                                  int* __restrict__ bh)
{
    __shared__ int hist[NBUCK];
    int t = threadIdx.x;
    int r = blockIdx.x / NBLK;
    int blk = blockIdx.x % NBLK;
    const int* dstE = edge_index + (size_t)r * 2 * E_EDGES + E_EDGES;
    for (int b = t; b < NBUCK; b += 256) hist[b] = 0;
    __syncthreads();
    int base = blk * CHUNK;
#pragma unroll 4
    for (int u = 0; u < CHUNK / 256; ++u) {
        int i = base + u * 256 + t;
        if (i < ETOT) {
            int d = (i < E_EDGES) ? dstE[i] : (i - E_EDGES);
            atomicAdd(&hist[d >> BSHIFT], 1);
        }
    }
    __syncthreads();
    int* bh_blk = bh + ((size_t)r * NBLK + blk) * NBUCK;
    for (int b = t; b < NBUCK; b += 256) bh_blk[b] = hist[b];
}

// Pass A2: per (r,bucket), exclusive scan of per-block counts -> bhoff + total.
__global__ __launch_bounds__(256) void partA2_scan(const int* __restrict__ bh,
                                                   int* __restrict__ bhoff,
                                                   int* __restrict__ btot)
{
    __shared__ int tmp[256];
    int r = blockIdx.x / NBUCK;
    int b = blockIdx.x % NBUCK;
    int t = threadIdx.x;
    const int* bh_r = bh + (size_t)r * NBLK * NBUCK;
    int* bhoff_r = bhoff + (size_t)r * NBLK * NBUCK;
    int v = (t < NBLK) ? bh_r[(size_t)t * NBUCK + b] : 0;   // NBLK=231 <= 256
    int x = v;
#pragma unroll
    for (int off = 1; off < 256; off <<= 1) {
        tmp[t] = x;
        __syncthreads();
        int a = (t >= off) ? tmp[t - off] : 0;
        __syncthreads();
        x += a;
    }
    if (t < NBLK) bhoff_r[(size_t)t * NBUCK + b] = x - v;
    if (t == 255) btot[r * NBUCK + b] = x;
}

// Pass A3: per relation, exclusive scan of bucket totals -> bucket bases.
__global__ __launch_bounds__(256) void partA3_scan(const int* __restrict__ btot,
                                                   int* __restrict__ bbase)
{
    __shared__ int tmp[256];
    __shared__ int carry_s;
    int r = blockIdx.x;
    int t = threadIdx.x;
    const int* row = btot + r * NBUCK;
    int* outb = bbase + r * (NBUCK + 1);
    if (t == 0) carry_s = 0;
    __syncthreads();
    for (int base = 0; base < NBUCK; base += 256) {
        int idx = base + t;
        int v = (idx < NBUCK) ? row[idx] : 0;
        int x = v;
#pragma unroll
        for (int off = 1; off < 256; off <<= 1) {
            tmp[t] = x;
            __syncthreads();
            int a = (t >= off) ? tmp[t - off] : 0;
            __syncthreads();
            x += a;
        }
        int carry = carry_s;
        if (idx < NBUCK) outb[idx] = carry + x - v;
        __syncthreads();
        if (t == 255) carry_s = carry + x;
        __syncthreads();
    }
    if (t == 0) outb[NBUCK] = carry_s;  // == ETOT
}

// Pass B: block-local LDS counting sort by bucket, then LINEAR coalesced write-out.
// Record: .x = src | (dst << 16) (both < 2^16), .y = w bits.
__global__ __launch_bounds__(256) void partB_scatter(
    const int* __restrict__ edge_index, const float* __restrict__ edge_weight,
    const int* __restrict__ bh, const int* __restrict__ bhoff,
    const int* __restrict__ bbase, int2* __restrict__ sedge)
{
    __shared__ int2 stage[CHUNK];     // 56 KB
    __shared__ int cur[NBUCK];
    __shared__ int gbase[NBUCK];
    __shared__ int tmp[256];
    __shared__ int carry_s;
    int t = threadIdx.x;
    int r = blockIdx.x / NBLK;
    int blk = blockIdx.x % NBLK;
    const int* srcE = edge_index + (size_t)r * 2 * E_EDGES;
    const int* dstE = srcE + E_EDGES;
    const float* ewr = edge_weight + (size_t)r * E_EDGES;
    const int* bh_blk = bh + ((size_t)r * NBLK + blk) * NBUCK;
    const int* bhoff_blk = bhoff + ((size_t)r * NBLK + blk) * NBUCK;
    const int* bbase_r = bbase + r * (NBUCK + 1);
    int2* se_r = sedge + (size_t)r * ETOT;

    if (t == 0) carry_s = 0;
    __syncthreads();
    for (int base = 0; base < NBUCK; base += 256) {
        int idx = base + t;
        int v = (idx < NBUCK) ? bh_blk[idx] : 0;
        int x = v;
#pragma unroll
        for (int off = 1; off < 256; off <<= 1) {
            tmp[t] = x;
            __syncthreads();
            int a = (t >= off) ? tmp[t - off] : 0;
            __syncthreads();
            x += a;
        }
        int carry = carry_s;
        if (idx < NBUCK) {
            int ls = carry + x - v;
            cur[idx] = ls;
            gbase[idx] = bbase_r[idx] + bhoff_blk[idx] - ls;
        }
        __syncthreads();
        if (t == 255) carry_s = carry + x;
        __syncthreads();
    }

    int base0 = blk * CHUNK;
    int chunkLen = ETOT - base0; if (chunkLen > CHUNK) chunkLen = CHUNK;
#pragma unroll 4
    for (int u = 0; u < CHUNK / 256; ++u) {
        int i = base0 + u * 256 + t;
        if (i < ETOT) {
            int s, d;
            float w;
            if (i < E_EDGES) {
                s = srcE[i]; d = dstE[i]; w = ewr[i];
            } else {
                s = d = i - E_EDGES; w = 1.0f;
            }
            int pos = atomicAdd(&cur[d >> BSHIFT], 1);  // LDS atomic
            int2 pay;
            pay.x = s | (d << 16);
            pay.y = __float_as_int(w);
            stage[pos] = pay;
        }
    }
    __syncthreads();
    for (int j = t; j < chunkLen; j += 256) {
        int2 rec = stage[j];
        int d = (int)(((unsigned)rec.x) >> 16);
        se_r[gbase[d >> BSHIFT] + j] = rec;
    }
}

// Pass C: per-bucket LDS-staged counting sort, IN PLACE in sedge -> rs + final {src,w}.
__global__ __launch_bounds__(256) void partC_sort(
    const int* __restrict__ bbase, int2* __restrict__ sedge,
    int* __restrict__ rs)
{
    __shared__ int2 stage[CCAP];   // 40 KB
    __shared__ int cnt[BSIZE];
    __shared__ int rsl[BSIZE];
    __shared__ int tmp[BSIZE];
    __shared__ int cur[BSIZE];
    int r = blockIdx.x / NBUCK;
    int b = blockIdx.x % NBUCK;
    int t = threadIdx.x;
    const int* bbase_r = bbase + r * (NBUCK + 1);
    int* rs_r = rs + r * (N_NODES + 1);
    int2* se_r = sedge + (size_t)r * ETOT;
    int lo = b * BSIZE;
    int nn = N_NODES - lo; if (nn > BSIZE) nn = BSIZE;
    int seg0 = bbase_r[b], seg1 = bbase_r[b + 1];
    int len = seg1 - seg0;
    if (t < BSIZE) { cnt[t] = 0; cur[t] = 0; }
    __syncthreads();
    for (int k = t; k < len; k += 256) {
        int2 pw = se_r[seg0 + k];   // coalesced read
        if (k < CCAP) stage[k] = pw;
        atomicAdd(&cnt[(pw.x >> 16) & (BSIZE - 1)], 1);
    }
    __syncthreads();
    int v = 0, x = 0;
    if (t < BSIZE) { v = cnt[t]; x = v; }
#pragma unroll
    for (int off = 1; off < BSIZE; off <<= 1) {
        if (t < BSIZE) tmp[t] = x;
        __syncthreads();
        int a = (t < BSIZE && t >= off) ? tmp[t - off] : 0;
        __syncthreads();
        x += a;
    }
    if (t < BSIZE) rsl[t] = x - v;  // local exclusive
    __syncthreads();
    if (t < nn) rs_r[lo + t] = seg0 + rsl[t];
    if (b == NBUCK - 1 && t == 0) rs_r[N_NODES] = seg1;
    for (int k = t; k < len; k += 256) {
        int2 pw = (k < CCAP) ? stage[k] : se_r[seg0 + k];
        int dlo = (pw.x >> 16) & (BSIZE - 1);
        int pos = rsl[dlo] + atomicAdd(&cur[dlo], 1);
        int2 rec;
        rec.x = pw.x & 0xFFFF;
        rec.y = pw.y;
        se_r[seg0 + pos] = rec;
    }
}

// ---------------- per-node softmax + aggregation (no max pass) ----------------
// One wave per dst node; blockIdx.y = relation. 2-stage pipelined gather with
// 4 independent accumulator chains. sedge loads are NONTEMPORAL (single-use
// stream; don't evict the h gather table from L2). Final-layer out stores nt.
__global__ __launch_bounds__(256) void agg_kernel(
    const int* __restrict__ rs, const int2* __restrict__ sedge,
    const float* __restrict__ as_v, const float* __restrict__ ad_v, size_t v_rstride,
    const float* __restrict__ h, size_t h_rstride,
    const float* __restrict__ bias, size_t b_rstride,
    float* __restrict__ out, size_t out_roffset, int out_stride, int do_relu,
    int r0)
{
    int rr = blockIdx.y;
    int rW = r0 + rr;
    rs += (size_t)rW * (N_NODES + 1);
    sedge += (size_t)rW * ETOT;
    as_v += (size_t)rr * v_rstride;
    ad_v += (size_t)rr * v_rstride;
    h += (size_t)rr * h_rstride;
    bias += (size_t)rW * b_rstride;
    out += (size_t)rr * out_roffset;

    int wave = (int)(((size_t)blockIdx.x * blockDim.x + threadIdx.x) >> 6);
    int lane = threadIdx.x & 63;
    if (wave >= N_NODES) return;
    int beg = rs[wave], end = rs[wave + 1];
    float ad_n = ad_v[wave];

    int sub = lane >> 4;   // edge sub-slot 0..3
    int f = lane & 15;     // feature quad index
    const float* hf = h + f * 4;

    float ssum = 0.f;
    float4 a0 = {0.f, 0.f, 0.f, 0.f};
    float4 a1 = a0, a2 = a0, a3 = a0;

    for (int cbeg = beg; cbeg < end; cbeg += 64) {
        int rem = end - cbeg;
        if (rem > 64) rem = 64;
        int srcv = 0;
        float pq = 0.f;
        if (lane < rem) {
            i32x2 pe = __builtin_nontemporal_load(
                reinterpret_cast<const i32x2*>(sedge + cbeg + lane));
            srcv = pe.x;
            float e = as_v[srcv] + ad_n;
            e = (e > 0.f) ? e : NEG_SLOPE * e;
            float p = __expf(e);
            ssum += p;
            pq = p * __int_as_float(pe.y);
        }
        int s0 = __shfl(srcv, sub, 64);
        float q0 = __shfl(pq, sub, 64);
        int s1 = __shfl(srcv, 4 + sub, 64);
        float q1 = __shfl(pq, 4 + sub, 64);
        int s2 = __shfl(srcv, 8 + sub, 64);
        float q2 = __shfl(pq, 8 + sub, 64);
        int s3 = __shfl(srcv, 12 + sub, 64);
        float q3 = __shfl(pq, 12 + sub, 64);
        float4 h0 = *reinterpret_cast<const float4*>(hf + (size_t)s0 * 64);
        float4 h1 = *reinterpret_cast<const float4*>(hf + (size_t)s1 * 64);
        float4 h2 = *reinterpret_cast<const float4*>(hf + (size_t)s2 * 64);
        float4 h3 = *reinterpret_cast<const float4*>(hf + (size_t)s3 * 64);
        for (int t0 = 16; t0 < rem; t0 += 16) {
            int ns0 = __shfl(srcv, t0 + sub, 64);
            float nq0 = __shfl(pq, t0 + sub, 64);
            int ns1 = __shfl(srcv, t0 + 4 + sub, 64);
            float nq1 = __shfl(pq, t0 + 4 + sub, 64);
            int ns2 = __shfl(srcv, t0 + 8 + sub, 64);
            float nq2 = __shfl(pq, t0 + 8 + sub, 64);
            int ns3 = __shfl(srcv, t0 + 12 + sub, 64);
            float nq3 = __shfl(pq, t0 + 12 + sub, 64);
            float4 nh0 = *reinterpret_cast<const float4*>(hf + (size_t)ns0 * 64);
            float4 nh1 = *reinterpret_cast<const float4*>(hf + (size_t)ns1 * 64);
            float4 nh2 = *reinterpret_cast<const float4*>(hf + (size_t)ns2 * 64);
            float4 nh3 = *reinterpret_cast<const float4*>(hf + (size_t)ns3 * 64);
            a0.x = fmaf(q0, h0.x, a0.x);
            a0.y = fmaf(q0, h0.y, a0.y);
            a0.z = fmaf(q0, h0.z, a0.z);
            a0.w = fmaf(q0, h0.w, a0.w);
            a1.x = fmaf(q1, h1.x, a1.x);
            a1.y = fmaf(q1, h1.y, a1.y);
            a1.z = fmaf(q1, h1.z, a1.z);
            a1.w = fmaf(q1, h1.w, a1.w);
            a2.x = fmaf(q2, h2.x, a2.x);
            a2.y = fmaf(q2, h2.y, a2.y);
            a2.z = fmaf(q2, h2.z, a2.z);
            a2.w = fmaf(q2, h2.w, a2.w);
            a3.x = fmaf(q3, h3.x, a3.x);
            a3.y = fmaf(q3, h3.y, a3.y);
            a3.z = fmaf(q3, h3.z, a3.z);
            a3.w = fmaf(q3, h3.w, a3.w);
            q0 = nq0; h0 = nh0;
            q1 = nq1; h1 = nh1;
            q2 = nq2; h2 = nh2;
            q3 = nq3; h3 = nh3;
        }
        a0.x = fmaf(q0, h0.x, a0.x);
        a0.y = fmaf(q0, h0.y, a0.y);
        a0.z = fmaf(q0, h0.z, a0.z);
        a0.w = fmaf(q0, h0.w, a0.w);
        a1.x = fmaf(q1, h1.x, a1.x);
        a1.y = fmaf(q1, h1.y, a1.y);
        a1.z = fmaf(q1, h1.z, a1.z);
        a1.w = fmaf(q1, h1.w, a1.w);
        a2.x = fmaf(q2, h2.x, a2.x);
        a2.y = fmaf(q2, h2.y, a2.y);
        a2.z = fmaf(q2, h2.z, a2.z);
        a2.w = fmaf(q2, h2.w, a2.w);
        a3.x = fmaf(q3, h3.x, a3.x);
        a3.y = fmaf(q3, h3.y, a3.y);
        a3.z = fmaf(q3, h3.z, a3.z);
        a3.w = fmaf(q3, h3.w, a3.w);
    }

    float4 acc;
    acc.x = (a0.x + a1.x) + (a2.x + a3.x);
    acc.y = (a0.y + a1.y) + (a2.y + a3.y);
    acc.z = (a0.z + a1.z) + (a2.z + a3.z);
    acc.w = (a0.w + a1.w) + (a2.w + a3.w);

#pragma unroll
    for (int off = 32; off > 0; off >>= 1) ssum += __shfl_xor(ssum, off, 64);
    acc.x += __shfl_xor(acc.x, 16, 64);
    acc.y += __shfl_xor(acc.y, 16, 64);
    acc.z += __shfl_xor(acc.z, 16, 64);
    acc.w += __shfl_xor(acc.w, 16, 64);
    acc.x += __shfl_xor(acc.x, 32, 64);
    acc.y += __shfl_xor(acc.y, 32, 64);
    acc.z += __shfl_xor(acc.z, 32, 64);
    acc.w += __shfl_xor(acc.w, 32, 64);

    if (sub == 0) {
        float inv = 1.f / (ssum + 1e-16f);
        const float4 bv = *reinterpret_cast<const float4*>(bias + f * 4);
        float4 o;
        o.x = fmaf(acc.x, inv, bv.x);
        o.y = fmaf(acc.y, inv, bv.y);
        o.z = fmaf(acc.z, inv, bv.z);
        o.w = fmaf(acc.w, inv, bv.w);
        float* dst = out + (size_t)wave * out_stride + f * 4;
        if (do_relu) {
            o.x = fmaxf(o.x, 0.f);
            o.y = fmaxf(o.y, 0.f);
            o.z = fmaxf(o.z, 0.f);
            o.w = fmaxf(o.w, 0.f);
            *reinterpret_cast<float4*>(dst) = o;   // xbuf: re-read by next gemm
        } else {
            f32x4 o4 = {o.x, o.y, o.z, o.w};       // final out: never re-read
            __builtin_nontemporal_store(o4, reinterpret_cast<f32x4*>(dst));
        }
    }
}

extern "C" void kernel_launch(void* const* d_in, const int* in_sizes, int n_in,
                              void* d_out, int out_size, void* d_ws, size_t ws_size,
                              hipStream_t stream)
{
    (void)in_sizes; (void)n_in; (void)out_size;
    const float* x = (const float*)d_in[0];
    const float* edge_weight = (const float*)d_in[1];
    const float* W0 = (const float*)d_in[2];
    const float* W1 = (const float*)d_in[3];
    const float* W2 = (const float*)d_in[4];
    const float* a_src = (const float*)d_in[5];
    const float* a_dst = (const float*)d_in[6];
    const float* bias = (const float*)d_in[7];
    const int* edge_index = (const int*)d_in[8];
    float* out = (float*)d_out;

    char* ws = (char*)d_ws;
    size_t off = 0;
    auto alloc = [&](size_t bytes) {
        void* p = ws + off;
        off += (bytes + 255) & ~(size_t)255;
        return p;
    };
    int2* sedge = (int2*)alloc((size_t)R_REL * ETOT * 8);        // 39.6 MB
    int* bh = (int*)alloc((size_t)R_REL * NBLK * NBUCK * 4);     // 1.08 MB
    int* bhoff = (int*)alloc((size_t)R_REL * NBLK * NBUCK * 4);  // 1.08 MB
    int* btot = (int*)alloc((size_t)R_REL * NBUCK * 4);
    int* bbase = (int*)alloc((size_t)R_REL * (NBUCK + 1) * 4);
    int* rs = (int*)alloc((size_t)R_REL * (N_NODES + 1) * 4);

    // batched path needs 3x node buffers (~78 MB extra); fall back if ws too small
    size_t per_rel = ((size_t)N_NODES * 64 * 4 * 2 + (size_t)N_NODES * 4 * 2 + 1024);
    int K = (ws_size >= off + 3 * per_rel + (1 << 20)) ? 3 : 1;
    float* hbuf = (float*)alloc((size_t)K * N_NODES * 64 * 4);
    float* xbuf = (float*)alloc((size_t)K * N_NODES * 64 * 4);
    float* asv = (float*)alloc((size_t)K * N_NODES * 4);
    float* adv = (float*)alloc((size_t)K * N_NODES * 4);

    const int WAVE_BLOCKS = (N_NODES * 64 + 255) / 256;  // 12500
    const int GEMM_BLOCKS = (N_NODES + 63) / 64;         // 782 (64 nodes/block)
    const size_t HS = (size_t)N_NODES * 64;              // per-relation h/x stride
    const size_t VS = (size_t)N_NODES;                   // per-relation asv/adv stride

    // batched CSR build for all 3 relations (5 launches, no global atomics)
    partA_hist<<<R_REL * NBLK, 256, 0, stream>>>(edge_index, bh);
    partA2_scan<<<R_REL * NBUCK, 256, 0, stream>>>(bh, bhoff, btot);
    partA3_scan<<<R_REL, 256, 0, stream>>>(btot, bbase);
    partB_scatter<<<R_REL * NBLK, 256, 0, stream>>>(edge_index, edge_weight,
                                                    bh, bhoff, bbase, sedge);
    partC_sort<<<R_REL * NBUCK, 256, 0, stream>>>(bbase, sedge, rs);

    if (K == 3) {
        // layer-lockstep: one gemm + one agg dispatch per layer, grid.y = 3 relations
        for (int i = 0; i < 3; ++i) {
            if (i == 0)
                gemm_alpha_kernel<D_IN><<<dim3(GEMM_BLOCKS, 3), 256, 0, stream>>>(
                    x, 0, W0, (size_t)D_IN * H_DIM,
                    a_src + i * H_DIM, a_dst + i * H_DIM, 3 * H_DIM,
                    hbuf, HS, asv, adv, VS, 0);
            else
                gemm_alpha_kernel<H_DIM><<<dim3(GEMM_BLOCKS, 3), 256, 0, stream>>>(
                    xbuf, HS, (i == 1 ? W1 : W2), (size_t)H_DIM * H_DIM,
                    a_src + i * H_DIM, a_dst + i * H_DIM, 3 * H_DIM,
                    hbuf, HS, asv, adv, VS, 0);
            if (i < 2)
                agg_kernel<<<dim3(WAVE_BLOCKS, 3), 256, 0, stream>>>(
                    rs, sedge, asv, adv, VS, hbuf, HS,
                    bias + i * H_DIM, 3 * H_DIM,
                    xbuf, HS, 64, 1, 0);
            else
                agg_kernel<<<dim3(WAVE_BLOCKS, 3), 256, 0, stream>>>(
                    rs, sedge, asv, adv, VS, hbuf, HS,
                    bias + i * H_DIM, 3 * H_DIM,
                    out, 64, 192, 0, 0);
        }
    } else {
        for (int r = 0; r < R_REL; ++r) {
            for (int i = 0; i < 3; ++i) {
                if (i == 0)
                    gemm_alpha_kernel<D_IN><<<dim3(GEMM_BLOCKS, 1), 256, 0, stream>>>(
                        x, 0, W0, (size_t)D_IN * H_DIM,
                        a_src + i * H_DIM, a_dst + i * H_DIM, 3 * H_DIM,
                        hbuf, 0, asv, adv, 0, r);
                else
                    gemm_alpha_kernel<H_DIM><<<dim3(GEMM_BLOCKS, 1), 256, 0, stream>>>(
                        xbuf, 0, (i == 1 ? W1 : W2), (size_t)H_DIM * H_DIM,
                        a_src + i * H_DIM, a_dst + i * H_DIM, 3 * H_DIM,
                        hbuf, 0, asv, adv, 0, r);
                if (i < 2)
                    agg_kernel<<<dim3(WAVE_BLOCKS, 1), 256, 0, stream>>>(
                        rs, sedge, asv, adv, 0, hbuf, 0,
                        bias + i * H_DIM, 3 * H_DIM,
                        xbuf, 0, 64, 1, r);
                else
                    agg_kernel<<<dim3(WAVE_BLOCKS, 1), 256, 0, stream>>>(
                        rs, sedge, asv, adv, 0, hbuf, 0,
                        bias + i * H_DIM, 3 * H_DIM,
                        out + r * 64, 0, 192, 0, r);
            }
        }
    }
}